// Round 4
// baseline (120.549 us; speedup 1.0000x reference)
//
#include <hip/hip_runtime.h>
#include <stdint.h>

// out[b,i,s] = (||w_i||^2 - 2*sum_o w[i,o]x[b,o,s] + ||x_{b,:,s}||^2) / K
// B=4, M=4096, K=1024, N=2048. fp32 in/out. bf16 32x32x16 MFMA cross term.
// 256x256 tile, BK=32, 8 waves, quad-buffered LDS, ONE barrier + ONE
// counted vmcnt(8) per K-tile, XOR-swizzled LDS, setprio, XCD swizzle,
// nontemporal output stores (keep wbf/xbT panels cache-resident).

#define M_DIM 4096
#define K_DIM 1024
#define N_DIM 2048
#define B_DIM 4

#define BM 256
#define BN 256
#define BK 32
#define NKT (K_DIM / BK)  // 32
#define MT (M_DIM / BM)   // 16
#define NT (N_DIM / BN)   // 8

typedef __attribute__((ext_vector_type(8))) __bf16 bf16x8;
typedef __attribute__((ext_vector_type(16))) float f32x16;
typedef __attribute__((ext_vector_type(4))) float f32x4v;  // native vec for nt-load

__device__ __forceinline__ ushort f2bf(float f) {
  uint32_t u = __float_as_uint(f);
  uint32_t r = (u + 0x7fffu + ((u >> 16) & 1u)) >> 16;  // RNE
  return (ushort)r;
}
__device__ __forceinline__ float bf2f(ushort u) {
  return __uint_as_float(((uint32_t)u) << 16);
}

// -------- prep_w -------------------------------------------------------------
__global__ __launch_bounds__(256) void prep_w(const float* __restrict__ w,
                                              ushort* __restrict__ wbf,
                                              float* __restrict__ w2) {
  const int i = blockIdx.x;
  const int t = threadIdx.x;
  f32x4v v = __builtin_nontemporal_load(((const f32x4v*)(w + (size_t)i * K_DIM)) + t);
  float ss = v.x * v.x + v.y * v.y + v.z * v.z + v.w * v.w;
  ushort4 o = make_ushort4(f2bf(v.x), f2bf(v.y), f2bf(v.z), f2bf(v.w));
  ((ushort4*)(wbf + (size_t)i * K_DIM))[t] = o;
#pragma unroll
  for (int off = 32; off > 0; off >>= 1) ss += __shfl_down(ss, off);
  __shared__ float red[4];
  if ((t & 63) == 0) red[t >> 6] = ss;
  __syncthreads();
  if (t == 0) w2[i] = red[0] + red[1] + red[2] + red[3];
}

// -------- prep_x -------------------------------------------------------------
__global__ __launch_bounds__(256) void prep_x(const float* __restrict__ x,
                                              ushort* __restrict__ xbT,
                                              float* __restrict__ x2) {
  __shared__ ushort tile[64][68];
  const int b = blockIdx.z;
  const int o0 = blockIdx.y * 64;
  const int s0 = blockIdx.x * 64;
  const int t = threadIdx.x;
  const int tr = t >> 4;
  const int tc = t & 15;
#pragma unroll
  for (int p = 0; p < 4; ++p) {
    const int r = p * 16 + tr;
    f32x4v v = __builtin_nontemporal_load(
        ((const f32x4v*)(x + ((size_t)(b * K_DIM + o0 + r)) * N_DIM + s0)) + tc);
    tile[r][tc * 4 + 0] = f2bf(v.x);
    tile[r][tc * 4 + 1] = f2bf(v.y);
    tile[r][tc * 4 + 2] = f2bf(v.z);
    tile[r][tc * 4 + 3] = f2bf(v.w);
  }
  __syncthreads();
#pragma unroll
  for (int p = 0; p < 4; ++p) {
    const int s = p * 16 + tr;
    ushort u0 = tile[tc * 4 + 0][s];
    ushort u1 = tile[tc * 4 + 1][s];
    ushort u2 = tile[tc * 4 + 2][s];
    ushort u3 = tile[tc * 4 + 3][s];
    float f0 = bf2f(u0), f1 = bf2f(u1), f2 = bf2f(u2), f3 = bf2f(u3);
    float ss = f0 * f0 + f1 * f1 + f2 * f2 + f3 * f3;
#pragma unroll
    for (int m = 1; m < 16; m <<= 1) ss += __shfl_xor(ss, m);
    if (tc == 0) atomicAdd(&x2[b * N_DIM + s0 + s], ss);
    *(ushort4*)(xbT + ((size_t)(b * N_DIM + s0 + s)) * K_DIM + o0 + tc * 4) =
        make_ushort4(u0, u1, u2, u3);
  }
}

// -------- GEMM ---------------------------------------------------------------
typedef const __attribute__((address_space(1))) uint32_t* gp_t;
typedef __attribute__((address_space(3))) uint32_t* lp_t;

__device__ __forceinline__ void gload_lds16(const void* g, const void* l) {
  __builtin_amdgcn_global_load_lds((gp_t)(uintptr_t)g,
                                   (lp_t)(uint32_t)(uintptr_t)l, 16, 0, 0);
}

#define MFMA32(a, b, c) __builtin_amdgcn_mfma_f32_32x32x16_bf16((a), (b), (c), 0, 0, 0)
#define FENCE() asm volatile("" ::: "memory")

__global__ __launch_bounds__(512, 2) void gemm_mse(
    const ushort* __restrict__ wbf, const ushort* __restrict__ xbT,
    const float* __restrict__ w2, const float* __restrict__ x2,
    float* __restrict__ out) {
  // LDS: A bufs 4x16KB at [0,64K), B bufs 4x16KB at [64K,128K)
  __shared__ __align__(16) char smem[131072];
  const int tid = threadIdx.x;
  const int wid = tid >> 6;
  const int lane = tid & 63;
  const int l31 = lane & 31;
  const int l5 = lane >> 5;
  const int wm = wid >> 2;  // 0..1
  const int wn = wid & 3;   // 0..3

  // XCD-aware block swizzle (512 blocks, 512%8==0 -> bijective)
  const int bid = blockIdx.x;
  const int swz = (bid & 7) * (MT * NT * B_DIM / 8) + (bid >> 3);
  const int m = swz & (MT - 1);
  const int nb = swz >> 4;
  const int n = nb & (NT - 1);
  const int bz = nb >> 3;

  const ushort* Ag = wbf + (size_t)m * BM * K_DIM;
  const ushort* Bg = xbT + ((size_t)bz * N_DIM + (size_t)n * BN) * K_DIM;

  // staging: slot s -> phys byte p=s*16; lin = p ^ (((p>>7)&3)<<4);
  // row = lin>>6 (64B = one 32-bf16 row), col = (lin&63)>>1
  const int p0 = tid * 16, p1 = (tid + 512) * 16;
  const int li0 = p0 ^ (((p0 >> 7) & 3) << 4);
  const int li1 = p1 ^ (((p1 >> 7) & 3) << 4);
  const size_t gOff0 = (size_t)(li0 >> 6) * K_DIM + ((li0 & 63) >> 1);
  const size_t gOff1 = (size_t)(li1 >> 6) * K_DIM + ((li1 & 63) >> 1);
  const int stA0 = wid * 1024, stA1 = 8192 + wid * 1024;
  const int stB0 = 65536 + wid * 1024, stB1 = 65536 + 8192 + wid * 1024;

#define STAGE_A(tt)                                    \
  {                                                    \
    const int bo_ = ((tt) & 3) * 16384;                \
    const int ko_ = (tt) * BK;                         \
    gload_lds16(Ag + gOff0 + ko_, smem + bo_ + stA0);  \
    gload_lds16(Ag + gOff1 + ko_, smem + bo_ + stA1);  \
  }
#define STAGE_B(tt)                                    \
  {                                                    \
    const int bo_ = ((tt) & 3) * 16384;                \
    const int ko_ = (tt) * BK;                         \
    gload_lds16(Bg + gOff0 + ko_, smem + bo_ + stB0);  \
    gload_lds16(Bg + gOff1 + ko_, smem + bo_ + stB1);  \
  }

  // frag bases: row = (wm*128|wn*64) + sub*32 + l31, lin = row*64 + l5*16 + h*32
  // mask = ((row>>1)&3)<<4 = ((l31>>1)&3)<<4 (sub*32, wm/wn offsets ≡ 0 mod 4 rows)
  const int mask = ((l31 >> 1) & 3) << 4;
  const int baseA0 = ((((wm * 128 + l31) << 6) | (l5 << 4)) ^ mask);
  const int baseA1 = baseA0 ^ 32;  // h=1: +32 on a bit that's clear pre-XOR
  const int baseB0 = 65536 + ((((wn * 64 + l31) << 6) | (l5 << 4)) ^ mask);
  const int baseB1 = baseB0 ^ 32;

#define LDA(mi, h, bo) (*(const bf16x8*)(smem + (bo) + ((h) ? baseA1 : baseA0) + (mi)*2048))
#define LDB(ni, h, bo) (*(const bf16x8*)(smem + (bo) + ((h) ? baseB1 : baseB0) + (ni)*2048))

  f32x16 acc[4][2] = {};

  // prologue: stage tiles 0,1,2; tile 0 landed at vmcnt(8)
  STAGE_A(0); STAGE_B(0);
  STAGE_A(1); STAGE_B(1);
  STAGE_A(2); STAGE_B(2);
  asm volatile("s_waitcnt vmcnt(8)" ::: "memory");
  __builtin_amdgcn_s_barrier();
  FENCE();

  for (int t = 0; t < NKT; ++t) {
    const int bo = (t & 3) * 16384;
    // frag reads for this tile (landed: vmcnt@t-1, visible: barrier@t-1)
    bf16x8 a00 = LDA(0, 0, bo), a10 = LDA(1, 0, bo), a20 = LDA(2, 0, bo), a30 = LDA(3, 0, bo);
    bf16x8 b00 = LDB(0, 0, bo), b10 = LDB(1, 0, bo);
    bf16x8 a01 = LDA(0, 1, bo), a11 = LDA(1, 1, bo), a21 = LDA(2, 1, bo), a31 = LDA(3, 1, bo);
    bf16x8 b01 = LDB(0, 1, bo), b11 = LDB(1, 1, bo);
    // stage tile t+3 (wraps into a dead buffer at the tail; keeps vmcnt uniform)
    const int tt = (t + 3) & (NKT - 1);
    STAGE_A(tt); STAGE_B(tt);
    // counted wait: 12 outstanding -> 8 leaves t+2,t+3 in flight; t+1 landed.
    asm volatile("s_waitcnt vmcnt(8)" ::: "memory");
    __builtin_amdgcn_s_setprio(1);
    acc[0][0] = MFMA32(a00, b00, acc[0][0]);
    acc[0][1] = MFMA32(a00, b10, acc[0][1]);
    acc[1][0] = MFMA32(a10, b00, acc[1][0]);
    acc[1][1] = MFMA32(a10, b10, acc[1][1]);
    acc[2][0] = MFMA32(a20, b00, acc[2][0]);
    acc[2][1] = MFMA32(a20, b10, acc[2][1]);
    acc[3][0] = MFMA32(a30, b00, acc[3][0]);
    acc[3][1] = MFMA32(a30, b10, acc[3][1]);
    acc[0][0] = MFMA32(a01, b01, acc[0][0]);
    acc[0][1] = MFMA32(a01, b11, acc[0][1]);
    acc[1][0] = MFMA32(a11, b01, acc[1][0]);
    acc[1][1] = MFMA32(a11, b11, acc[1][1]);
    acc[2][0] = MFMA32(a21, b01, acc[2][0]);
    acc[2][1] = MFMA32(a21, b11, acc[2][1]);
    acc[3][0] = MFMA32(a31, b01, acc[3][0]);
    acc[3][1] = MFMA32(a31, b11, acc[3][1]);
    __builtin_amdgcn_s_setprio(0);
    // all ds_reads consumed by MFMA; drain lgkm so the barrier proves
    // read-completion before any wave's next-iter staging overwrites buf t-1.
    asm volatile("s_waitcnt lgkmcnt(0)" ::: "memory");
    __builtin_amdgcn_sched_barrier(0);
    __builtin_amdgcn_s_barrier();
    FENCE();
  }

  // epilogue: out = (w2[i] - 2*acc + x2[b,s]) / K
  // 32x32 C/D: col = l31, row = (reg&3) + 8*(reg>>2) + 4*l5   [m74/m101]
  const float inv = 1.0f / (float)K_DIM;
  const int rowb = m * BM + wm * 128 + 4 * l5;
  const int colb = n * BN + wn * 64 + l31;
  const float xv0 = x2[bz * N_DIM + colb];
  const float xv1 = x2[bz * N_DIM + colb + 32];
  float* outb = out + (size_t)bz * M_DIM * N_DIM;
#pragma unroll
  for (int mi = 0; mi < 4; ++mi) {
#pragma unroll
    for (int r4 = 0; r4 < 4; ++r4) {
#pragma unroll
      for (int r = 0; r < 4; ++r) {
        const int reg = r4 * 4 + r;
        const int row = rowb + mi * 32 + 8 * r4 + r;
        const float wv = w2[row];
        float* orow = outb + (size_t)row * N_DIM + colb;
        __builtin_nontemporal_store((wv - 2.0f * acc[mi][0][reg] + xv0) * inv, orow);
        __builtin_nontemporal_store((wv - 2.0f * acc[mi][1][reg] + xv1) * inv, orow + 32);
      }
    }
  }
#undef STAGE_A
#undef STAGE_B
#undef LDA
#undef LDB
}

// -------- launcher -----------------------------------------------------------
extern "C" void kernel_launch(void* const* d_in, const int* in_sizes, int n_in,
                              void* d_out, int out_size, void* d_ws, size_t ws_size,
                              hipStream_t stream) {
  const float* x = (const float*)d_in[0];  // (4, 1024, 2048)
  const float* w = (const float*)d_in[1];  // (4096, 1024)
  float* out = (float*)d_out;              // (4, 4096, 2048)
  char* ws = (char*)d_ws;
  ushort* wbf = (ushort*)ws;                        // 8 MB
  ushort* xbT = (ushort*)(ws + (size_t)(8 << 20));  // 16 MB
  float* w2 = (float*)(ws + (size_t)(24 << 20));    // 16 KB
  float* x2 = w2 + M_DIM;                           // 32 KB

  (void)hipMemsetAsync(x2, 0, B_DIM * N_DIM * sizeof(float), stream);
  prep_w<<<dim3(M_DIM), dim3(256), 0, stream>>>(w, wbf, w2);
  prep_x<<<dim3(N_DIM / 64, K_DIM / 64, B_DIM), dim3(256), 0, stream>>>(x, xbT, x2);
  gemm_mse<<<dim3(MT * NT * B_DIM), dim3(512), 0, stream>>>(wbf, xbT, w2, x2, out);
}